// Round 2
// baseline (484.822 us; speedup 1.0000x reference)
//
#include <hip/hip_runtime.h>

#define T_    1024
#define H_    1024
#define IDIM  1024
#define E_    16
#define TOPK  4
#define ALPHA 1.702f
#define LIMIT 7.0f

typedef __bf16 bf16;
typedef __bf16 bf16x4 __attribute__((ext_vector_type(4)));
typedef __bf16 bf16x8 __attribute__((ext_vector_type(8)));
typedef float  f32x4  __attribute__((ext_vector_type(4)));

// ---------------------------------------------------------------------------
// Kernel 1: RMSNorm + router logits + softmax/top-4 + routing lists.
// ---------------------------------------------------------------------------
__global__ __launch_bounds__(256) void k_rms_router(
    const float* __restrict__ x, const float* __restrict__ nw,
    const float* __restrict__ rw, const float* __restrict__ rb,
    const float* __restrict__ mw, const int* __restrict__ lidx,
    bf16* __restrict__ tB, float* __restrict__ out,
    int* __restrict__ cnt, int* __restrict__ tok_list,
    float* __restrict__ wgt_list)
{
    const int t = blockIdx.x, tid = threadIdx.x;
    const int lane = tid & 63, wave = tid >> 6;
    __shared__ float tbuf[H_];
    __shared__ float red[4];
    __shared__ float logits[E_];

    float4 xv = ((const float4*)(x + (size_t)t * H_))[tid];
    float4 wv = ((const float4*)nw)[tid];
    float ssq = xv.x*xv.x + xv.y*xv.y + xv.z*xv.z + xv.w*xv.w;
    #pragma unroll
    for (int off = 32; off; off >>= 1) ssq += __shfl_xor(ssq, off);
    if (lane == 0) red[wave] = ssq;
    __syncthreads();
    const float rms = rsqrtf((red[0] + red[1] + red[2] + red[3]) * (1.0f / H_) + 1e-5f);

    float4 tv;
    tv.x = xv.x * rms * wv.x;
    tv.y = xv.y * rms * wv.y;
    tv.z = xv.z * rms * wv.z;
    tv.w = xv.w * rms * wv.w;

    ((float4*)(out + (size_t)t * H_))[tid] = xv;      // residual init
    ((float4*)tbuf)[tid] = tv;
    bf16x4 tb = { (bf16)tv.x, (bf16)tv.y, (bf16)tv.z, (bf16)tv.w };
    *(bf16x4*)(tB + (size_t)t * H_ + tid * 4) = tb;
    __syncthreads();

    #pragma unroll
    for (int ei = 0; ei < 4; ++ei) {
        const int e = wave * 4 + ei;
        const float* wr = rw + (size_t)e * H_;
        float s = 0.f;
        #pragma unroll
        for (int j = 0; j < 16; ++j) {
            const int c = lane + j * 64;
            s += tbuf[c] * wr[c];
        }
        #pragma unroll
        for (int off = 32; off; off >>= 1) s += __shfl_xor(s, off);
        if (lane == 0) logits[e] = s + rb[e];
    }
    __syncthreads();

    if (tid == 0) {
        float g[E_];
        #pragma unroll
        for (int e = 0; e < E_; ++e) g[e] = logits[e];

        const int li = lidx[0];
        float ma = 0.f, lw[E_];
        #pragma unroll
        for (int e = 0; e < E_; ++e) { lw[e] = mw[li * E_ + e]; ma = fmaxf(ma, fabsf(lw[e])); }
        if (ma > 0.f) {
            float mx = -1e30f;
            for (int e = 0; e < E_; ++e) mx = fmaxf(mx, g[e]);
            float se = 0.f;
            for (int e = 0; e < E_; ++e) se += expf(g[e] - mx);
            const float lse = logf(se) + mx;
            float gl[E_], gmx = -1e30f, gmn = 1e30f;
            for (int e = 0; e < E_; ++e) { gl[e] = g[e] - lse; gmx = fmaxf(gmx, gl[e]); gmn = fminf(gmn, gl[e]); }
            for (int e = 0; e < E_; ++e) {
                if (lw[e] > 0.f)      gl[e] = gmx + 0.01f;
                else if (lw[e] < 0.f) gl[e] = gmn - 0.01f;
                g[e] = gl[e];
            }
        }

        float mx = -1e30f;
        #pragma unroll
        for (int e = 0; e < E_; ++e) mx = fmaxf(mx, g[e]);
        float p[E_];
        #pragma unroll
        for (int e = 0; e < E_; ++e) p[e] = expf(g[e] - mx);

        bool used[E_] = {};
        int   idx[TOPK];
        float twv[TOPK];
        float ssum = 0.f;
        for (int k = 0; k < TOPK; ++k) {
            int best = -1; float bv = -1e30f;
            for (int e = 0; e < E_; ++e)
                if (!used[e] && p[e] > bv) { bv = p[e]; best = e; }
            used[best] = true; idx[k] = best; twv[k] = bv; ssum += bv;
        }
        const float inv = 1.f / ssum;
        for (int k = 0; k < TOPK; ++k) {
            const int e = idx[k];
            const int slot = atomicAdd(&cnt[e], 1);
            tok_list[e * T_ + slot] = t;
            wgt_list[e * T_ + slot] = twv[k] * inv;
        }
    }
}

__global__ void k_scan(const int* __restrict__ cnt, int* __restrict__ base)
{
    if (threadIdx.x == 0) {
        int s = 0;
        for (int e = 0; e < E_; ++e) { base[e] = s; s += cnt[e]; }
        base[E_] = s;
    }
}

// ---------------------------------------------------------------------------
// Repack: W [E][1024(k)][Ndim(n)] fp32 -> bf16 MFMA-fragment tiles.
// out[((e*(Ndim/16) + nb)*32 + kb)*512 + l*8 + j] = W[e][kb*32+(l>>4)*8+j][nb*16+(l&15)]
// grid: (Ndim/256, 32, E_), block 256.
// ---------------------------------------------------------------------------
__global__ __launch_bounds__(256) void k_repack(
    const float* __restrict__ W, bf16* __restrict__ out, int Ndim)
{
    __shared__ float tile[32][260];           // pad 4: float4-aligned rows
    const int e = blockIdx.z, kb = blockIdx.y, n0 = blockIdx.x * 256;
    const int t = threadIdx.x;
    const int nbs = Ndim >> 4;

    const float* src = W + ((size_t)e * 1024 + (size_t)kb * 32) * Ndim + n0;
    #pragma unroll
    for (int i = 0; i < 8; ++i) {
        const int idx = i * 256 + t;
        const int k = idx >> 6, c4 = (idx & 63) * 4;
        float4 v = *(const float4*)(src + (size_t)k * Ndim + c4);
        *(float4*)&tile[k][c4] = v;
    }
    __syncthreads();

    const int f = t >> 4;                     // fragment 0..15 (nb offset)
    const int lg = (t & 15) * 4;              // 4 lanes per thread
    bf16* dst = out + (((size_t)(e * nbs + n0 / 16 + f)) * 32 + kb) * 512;
    #pragma unroll
    for (int li = 0; li < 4; ++li) {
        const int l = lg + li, q = l >> 4, r = l & 15;
        bf16x8 p;
        #pragma unroll
        for (int j = 0; j < 8; ++j) p[j] = (bf16)tile[q * 8 + j][f * 16 + r];
        *(bf16x8*)(dst + l * 8) = p;
    }
}

// ---------------------------------------------------------------------------
// Kernel 3 (fast): grouped gate_up GEMM from packed bf16 weights.
// No LDS, no barriers. Block 256 = 4 waves; wave = 64m x 32n(gate)+32n(up).
// 2-stage register pipeline; 16 MFMA / k32-step / wave.
// grid: (8, 16, E_).
// ---------------------------------------------------------------------------
__global__ __launch_bounds__(256) void k_gateup2(
    const bf16* __restrict__ tB, const bf16* __restrict__ w13p,
    const float* __restrict__ b13, const int* __restrict__ cnt,
    const int* __restrict__ base, const int* __restrict__ tok_list,
    bf16* __restrict__ act)
{
    const int e  = blockIdx.z;
    const int ne = cnt[e];
    const int m0 = blockIdx.y * 64;
    if (m0 >= ne) return;
    const int wave = threadIdx.x >> 6, lane = threadIdx.x & 63;
    const int q = lane >> 4, r = lane & 15;
    const int nb0 = blockIdx.x * 8 + wave * 2;      // gate nb in [0,64)

    // A per-lane row pointers (gathered tokens, clamped)
    const bf16* pA0; const bf16* pA1; const bf16* pA2; const bf16* pA3;
    {
        const int* tl = tok_list + e * T_;
        int s0 = m0 + 0  + r; s0 = s0 < ne ? s0 : ne - 1;
        int s1 = m0 + 16 + r; s1 = s1 < ne ? s1 : ne - 1;
        int s2 = m0 + 32 + r; s2 = s2 < ne ? s2 : ne - 1;
        int s3 = m0 + 48 + r; s3 = s3 < ne ? s3 : ne - 1;
        pA0 = tB + (size_t)tl[s0] * H_ + q * 8;
        pA1 = tB + (size_t)tl[s1] * H_ + q * 8;
        pA2 = tB + (size_t)tl[s2] * H_ + q * 8;
        pA3 = tB + (size_t)tl[s3] * H_ + q * 8;
    }
    const bf16* pBg0 = w13p + ((size_t)(e * 128 + nb0     ) * 32) * 512 + lane * 8;
    const bf16* pBg1 = w13p + ((size_t)(e * 128 + nb0 + 1 ) * 32) * 512 + lane * 8;
    const bf16* pBu0 = w13p + ((size_t)(e * 128 + nb0 + 64) * 32) * 512 + lane * 8;
    const bf16* pBu1 = w13p + ((size_t)(e * 128 + nb0 + 65) * 32) * 512 + lane * 8;

    f32x4 accg[4][2] = {};
    f32x4 accu[4][2] = {};
    bf16x8 a0[4], b0[4], a1[4], b1[4];

#define LOADG(A, B) do { \
    A[0] = *(const bf16x8*)pA0; pA0 += 32; \
    A[1] = *(const bf16x8*)pA1; pA1 += 32; \
    A[2] = *(const bf16x8*)pA2; pA2 += 32; \
    A[3] = *(const bf16x8*)pA3; pA3 += 32; \
    B[0] = *(const bf16x8*)pBg0; pBg0 += 512; \
    B[1] = *(const bf16x8*)pBg1; pBg1 += 512; \
    B[2] = *(const bf16x8*)pBu0; pBu0 += 512; \
    B[3] = *(const bf16x8*)pBu1; pBu1 += 512; } while (0)

#define COMPG(A, B) do { \
    _Pragma("unroll") \
    for (int mf = 0; mf < 4; ++mf) { \
        accg[mf][0] = __builtin_amdgcn_mfma_f32_16x16x32_bf16(A[mf], B[0], accg[mf][0], 0, 0, 0); \
        accg[mf][1] = __builtin_amdgcn_mfma_f32_16x16x32_bf16(A[mf], B[1], accg[mf][1], 0, 0, 0); \
        accu[mf][0] = __builtin_amdgcn_mfma_f32_16x16x32_bf16(A[mf], B[2], accu[mf][0], 0, 0, 0); \
        accu[mf][1] = __builtin_amdgcn_mfma_f32_16x16x32_bf16(A[mf], B[3], accu[mf][1], 0, 0, 0); \
    } } while (0)

    LOADG(a0, b0);
    for (int kb = 0; kb < 30; kb += 2) {
        LOADG(a1, b1); COMPG(a0, b0);
        LOADG(a0, b0); COMPG(a1, b1);
    }
    LOADG(a1, b1); COMPG(a0, b0); COMPG(a1, b1);
#undef LOADG
#undef COMPG

    const int sb = base[e];
    #pragma unroll
    for (int mf = 0; mf < 4; ++mf) {
        #pragma unroll
        for (int nf = 0; nf < 2; ++nf) {
            const int cg = (nb0 + nf) * 16 + r;
            const float bg = b13[e * 2 * IDIM + cg];
            const float bu = b13[e * 2 * IDIM + IDIM + cg];
            #pragma unroll
            for (int rg = 0; rg < 4; ++rg) {
                const int row = mf * 16 + q * 4 + rg;
                if (m0 + row < ne) {
                    const float hg = accg[mf][nf][rg] + bg;
                    const float hu = accu[mf][nf][rg] + bu;
                    const float gt = fminf(hg, LIMIT);
                    const float up = fminf(fmaxf(hu, -LIMIT), LIMIT);
                    const float av = (up + 1.0f) * gt / (1.0f + expf(-ALPHA * gt));
                    act[(size_t)(sb + m0 + row) * IDIM + cg] = (bf16)av;
                }
            }
        }
    }
}

// ---------------------------------------------------------------------------
// Kernel 4 (fast): grouped down GEMM from packed bf16 w2 + weighted combine.
// grid: (8, 16, E_).
// ---------------------------------------------------------------------------
__global__ __launch_bounds__(256) void k_down2(
    const bf16* __restrict__ act, const bf16* __restrict__ w2p,
    const float* __restrict__ b2, const int* __restrict__ cnt,
    const int* __restrict__ base, const int* __restrict__ tok_list,
    const float* __restrict__ wgt_list, float* __restrict__ out)
{
    const int e  = blockIdx.z;
    const int ne = cnt[e];
    const int m0 = blockIdx.y * 64;
    if (m0 >= ne) return;
    const int sb = base[e];
    const int wave = threadIdx.x >> 6, lane = threadIdx.x & 63;
    const int q = lane >> 4, r = lane & 15;
    const int nb0 = blockIdx.x * 8 + wave * 2;      // h nb in [0,64)

    const bf16* pA0; const bf16* pA1; const bf16* pA2; const bf16* pA3;
    {
        int s0 = m0 + 0  + r; s0 = s0 < ne ? s0 : ne - 1;
        int s1 = m0 + 16 + r; s1 = s1 < ne ? s1 : ne - 1;
        int s2 = m0 + 32 + r; s2 = s2 < ne ? s2 : ne - 1;
        int s3 = m0 + 48 + r; s3 = s3 < ne ? s3 : ne - 1;
        pA0 = act + (size_t)(sb + s0) * IDIM + q * 8;
        pA1 = act + (size_t)(sb + s1) * IDIM + q * 8;
        pA2 = act + (size_t)(sb + s2) * IDIM + q * 8;
        pA3 = act + (size_t)(sb + s3) * IDIM + q * 8;
    }
    const bf16* pB0 = w2p + ((size_t)(e * 64 + nb0    ) * 32) * 512 + lane * 8;
    const bf16* pB1 = w2p + ((size_t)(e * 64 + nb0 + 1) * 32) * 512 + lane * 8;

    f32x4 acc[4][2] = {};
    bf16x8 a0[4], b0[2], a1[4], b1[2];

#define LOADD(A, B) do { \
    A[0] = *(const bf16x8*)pA0; pA0 += 32; \
    A[1] = *(const bf16x8*)pA1; pA1 += 32; \
    A[2] = *(const bf16x8*)pA2; pA2 += 32; \
    A[3] = *(const bf16x8*)pA3; pA3 += 32; \
    B[0] = *(const bf16x8*)pB0; pB0 += 512; \
    B[1] = *(const bf16x8*)pB1; pB1 += 512; } while (0)

#define COMPD(A, B) do { \
    _Pragma("unroll") \
    for (int mf = 0; mf < 4; ++mf) { \
        acc[mf][0] = __builtin_amdgcn_mfma_f32_16x16x32_bf16(A[mf], B[0], acc[mf][0], 0, 0, 0); \
        acc[mf][1] = __builtin_amdgcn_mfma_f32_16x16x32_bf16(A[mf], B[1], acc[mf][1], 0, 0, 0); \
    } } while (0)

    LOADD(a0, b0);
    for (int kb = 0; kb < 30; kb += 2) {
        LOADD(a1, b1); COMPD(a0, b0);
        LOADD(a0, b0); COMPD(a1, b1);
    }
    LOADD(a1, b1); COMPD(a0, b0); COMPD(a1, b1);
#undef LOADD
#undef COMPD

    #pragma unroll
    for (int mf = 0; mf < 4; ++mf) {
        #pragma unroll
        for (int nf = 0; nf < 2; ++nf) {
            const int ch = (nb0 + nf) * 16 + r;
            const float bb = b2[e * H_ + ch];
            #pragma unroll
            for (int rg = 0; rg < 4; ++rg) {
                const int row = mf * 16 + q * 4 + rg;
                const int s = m0 + row;
                if (s < ne) {
                    const int   tok = tok_list[e * T_ + s];
                    const float w   = wgt_list[e * T_ + s];
                    atomicAdd(&out[(size_t)tok * H_ + ch], w * (acc[mf][nf][rg] + bb));
                }
            }
        }
    }
}

// ---------------------------------------------------------------------------
// Fallback (round-1) GEMMs: LDS-staged, inline fp32->bf16. Used if ws is small.
// ---------------------------------------------------------------------------
__global__ __launch_bounds__(256) void k_gateup(
    const bf16* __restrict__ tB, const float* __restrict__ w13,
    const float* __restrict__ b13, const int* __restrict__ cnt,
    const int* __restrict__ base, const int* __restrict__ tok_list,
    bf16* __restrict__ act)
{
    const int e  = blockIdx.z;
    const int ne = cnt[e];
    const int m0 = blockIdx.y * 64;
    if (m0 >= ne) return;
    const int n0  = blockIdx.x * 64;
    const int tid = threadIdx.x, lane = tid & 63, wave = tid >> 6;

    __shared__ __align__(16) bf16 As[64][40];
    __shared__ __align__(16) bf16 Bg[64][40];
    __shared__ __align__(16) bf16 Bu[64][40];
    __shared__ int stok[64];

    if (tid < 64) {
        const int s = m0 + tid;
        stok[tid] = (s < ne) ? tok_list[e * T_ + s] : -1;
    }
    __syncthreads();

    const int ar = tid >> 2, ak = (tid & 3) * 8;
    const int atok = stok[ar];
    const int bn = tid & 63, bk = wave * 8;
    const size_t wrow = (size_t)(2 * IDIM);
    const float* wbase = w13 + (size_t)e * H_ * wrow + n0 + bn;

    const int wm = wave >> 1, wn = wave & 1;
    const int q = lane >> 4, r = lane & 15;
    f32x4 accg[2][2] = {};
    f32x4 accu[2][2] = {};

    for (int kb = 0; kb < H_ / 32; ++kb) {
        __syncthreads();
        uint4 av = make_uint4(0u, 0u, 0u, 0u);
        if (atok >= 0)
            av = *(const uint4*)(tB + (size_t)atok * H_ + kb * 32 + ak);
        *(uint4*)&As[ar][ak] = av;
        {
            const float* src = wbase + (size_t)(kb * 32 + bk) * wrow;
            bf16x8 pg, pu;
            #pragma unroll
            for (int j = 0; j < 8; ++j) {
                pg[j] = (bf16)src[(size_t)j * wrow];
                pu[j] = (bf16)src[(size_t)j * wrow + IDIM];
            }
            *(bf16x8*)&Bg[bn][bk] = pg;
            *(bf16x8*)&Bu[bn][bk] = pu;
        }
        __syncthreads();
        bf16x8 a[2], bg[2], bu[2];
        a[0]  = *(const bf16x8*)&As[wm * 32 +      r][q * 8];
        a[1]  = *(const bf16x8*)&As[wm * 32 + 16 + r][q * 8];
        bg[0] = *(const bf16x8*)&Bg[wn * 32 +      r][q * 8];
        bg[1] = *(const bf16x8*)&Bg[wn * 32 + 16 + r][q * 8];
        bu[0] = *(const bf16x8*)&Bu[wn * 32 +      r][q * 8];
        bu[1] = *(const bf16x8*)&Bu[wn * 32 + 16 + r][q * 8];
        #pragma unroll
        for (int im = 0; im < 2; ++im)
            #pragma unroll
            for (int in = 0; in < 2; ++in) {
                accg[im][in] = __builtin_amdgcn_mfma_f32_16x16x32_bf16(a[im], bg[in], accg[im][in], 0, 0, 0);
                accu[im][in] = __builtin_amdgcn_mfma_f32_16x16x32_bf16(a[im], bu[in], accu[im][in], 0, 0, 0);
            }
    }

    const int sb = base[e];
    #pragma unroll
    for (int im = 0; im < 2; ++im)
        #pragma unroll
        for (int in = 0; in < 2; ++in)
            #pragma unroll
            for (int rg = 0; rg < 4; ++rg) {
                const int row = wm * 32 + im * 16 + q * 4 + rg;
                const int col = wn * 32 + in * 16 + r;
                if (m0 + row < ne) {
                    const float hg = accg[im][in][rg] + b13[e * 2 * IDIM + n0 + col];
                    const float hu = accu[im][in][rg] + b13[e * 2 * IDIM + IDIM + n0 + col];
                    const float gt = fminf(hg, LIMIT);
                    const float up = fminf(fmaxf(hu, -LIMIT), LIMIT);
                    const float av = (up + 1.0f) * gt / (1.0f + expf(-ALPHA * gt));
                    act[(size_t)(sb + m0 + row) * IDIM + n0 + col] = (bf16)av;
                }
            }
}

__global__ __launch_bounds__(256) void k_down(
    const bf16* __restrict__ act, const float* __restrict__ w2,
    const float* __restrict__ b2, const int* __restrict__ cnt,
    const int* __restrict__ base, const int* __restrict__ tok_list,
    const float* __restrict__ wgt_list, float* __restrict__ out)
{
    const int e  = blockIdx.z;
    const int ne = cnt[e];
    const int m0 = blockIdx.y * 64;
    if (m0 >= ne) return;
    const int n0  = blockIdx.x * 64;
    const int tid = threadIdx.x, lane = tid & 63, wave = tid >> 6;

    __shared__ __align__(16) bf16 As[64][40];
    __shared__ __align__(16) bf16 Bs[64][40];
    __shared__ int   stok[64];
    __shared__ float swgt[64];

    if (tid < 64) {
        const int s = m0 + tid;
        stok[tid] = (s < ne) ? tok_list[e * T_ + s] : -1;
        swgt[tid] = (s < ne) ? wgt_list[e * T_ + s] : 0.f;
    }
    __syncthreads();

    const int sb = base[e];
    const int ar = tid >> 2, ak = (tid & 3) * 8;
    const bool arow_ok = (m0 + ar) < ne;
    const int bn = tid & 63, bk = wave * 8;
    const float* wbase = w2 + (size_t)e * IDIM * H_ + n0 + bn;

    const int wm = wave >> 1, wn = wave & 1;
    const int q = lane >> 4, r = lane & 15;
    f32x4 acc[2][2] = {};

    for (int kb = 0; kb < IDIM / 32; ++kb) {
        __syncthreads();
        uint4 av = make_uint4(0u, 0u, 0u, 0u);
        if (arow_ok)
            av = *(const uint4*)(act + (size_t)(sb + m0 + ar) * IDIM + kb * 32 + ak);
        *(uint4*)&As[ar][ak] = av;
        {
            const float* src = wbase + (size_t)(kb * 32 + bk) * H_;
            bf16x8 pb;
            #pragma unroll
            for (int j = 0; j < 8; ++j) pb[j] = (bf16)src[(size_t)j * H_];
            *(bf16x8*)&Bs[bn][bk] = pb;
        }
        __syncthreads();
        bf16x8 a[2], b[2];
        a[0] = *(const bf16x8*)&As[wm * 32 +      r][q * 8];
        a[1] = *(const bf16x8*)&As[wm * 32 + 16 + r][q * 8];
        b[0] = *(const bf16x8*)&Bs[wn * 32 +      r][q * 8];
        b[1] = *(const bf16x8*)&Bs[wn * 32 + 16 + r][q * 8];
        #pragma unroll
        for (int im = 0; im < 2; ++im)
            #pragma unroll
            for (int in = 0; in < 2; ++in)
                acc[im][in] = __builtin_amdgcn_mfma_f32_16x16x32_bf16(a[im], b[in], acc[im][in], 0, 0, 0);
    }

    #pragma unroll
    for (int im = 0; im < 2; ++im)
        #pragma unroll
        for (int in = 0; in < 2; ++in)
            #pragma unroll
            for (int rg = 0; rg < 4; ++rg) {
                const int row = wm * 32 + im * 16 + q * 4 + rg;
                const int col = wn * 32 + in * 16 + r;
                if (m0 + row < ne) {
                    const int   tok = stok[row];
                    const float w   = swgt[row];
                    atomicAdd(&out[(size_t)tok * H_ + n0 + col], w * (acc[im][in][rg] + b2[e * H_ + n0 + col]));
                }
            }
}

// ---------------------------------------------------------------------------
extern "C" void kernel_launch(void* const* d_in, const int* in_sizes, int n_in,
                              void* d_out, int out_size, void* d_ws, size_t ws_size,
                              hipStream_t stream)
{
    const float* x        = (const float*)d_in[0];
    const float* norm_w   = (const float*)d_in[1];
    const float* router_w = (const float*)d_in[2];
    const float* router_b = (const float*)d_in[3];
    const float* w13      = (const float*)d_in[4];
    const float* b13      = (const float*)d_in[5];
    const float* w2       = (const float*)d_in[6];
    const float* b2       = (const float*)d_in[7];
    const float* manual_w = (const float*)d_in[8];
    const int*   layer_i  = (const int*)d_in[9];
    float* out = (float*)d_out;

    char* ws = (char*)d_ws;
    bf16*  tB       = (bf16*)ws;                               // 2 MB
    bf16*  act      = (bf16*)(ws + (2ull << 20));              // 8 MB
    int*   cnt      = (int*)(ws + (10ull << 20));
    int*   basep    = cnt + E_;
    int*   tok_list = (int*)(ws + (10ull << 20) + 256);
    float* wgt_list = (float*)(ws + (10ull << 20) + 256 + (64ull << 10));
    bf16*  w13p     = (bf16*)(ws + (12ull << 20));             // 64 MB
    bf16*  w2p      = (bf16*)(ws + (76ull << 20));             // 32 MB

    const bool fast = ws_size >= (108ull << 20);

    hipMemsetAsync(cnt, 0, E_ * sizeof(int), stream);

    k_rms_router<<<T_, 256, 0, stream>>>(x, norm_w, router_w, router_b,
                                         manual_w, layer_i, tB, out,
                                         cnt, tok_list, wgt_list);
    k_scan<<<1, 64, 0, stream>>>(cnt, basep);

    if (fast) {
        dim3 gr13(2 * IDIM / 256, 32, E_);
        k_repack<<<gr13, 256, 0, stream>>>(w13, w13p, 2 * IDIM);
        dim3 gr2(H_ / 256, 32, E_);
        k_repack<<<gr2, 256, 0, stream>>>(w2, w2p, H_);

        dim3 gg(8, 16, E_);
        k_gateup2<<<gg, 256, 0, stream>>>(tB, w13p, b13, cnt, basep, tok_list, act);
        dim3 gd(8, 16, E_);
        k_down2<<<gd, 256, 0, stream>>>(act, w2p, b2, cnt, basep, tok_list, wgt_list, out);
    } else {
        dim3 gg(IDIM / 64, T_ / 64, E_);
        k_gateup<<<gg, 256, 0, stream>>>(tB, w13, b13, cnt, basep, tok_list, act);
        dim3 gd(H_ / 64, T_ / 64, E_);
        k_down<<<gd, 256, 0, stream>>>(act, w2, b2, cnt, basep, tok_list, wgt_list, out);
    }
}

// Round 3
// 403.061 us; speedup vs baseline: 1.2028x; 1.2028x over previous
//
#include <hip/hip_runtime.h>

#define T_    1024
#define H_    1024
#define IDIM  1024
#define E_    16
#define TOPK  4
#define ALPHA 1.702f
#define LIMIT 7.0f

typedef __bf16 bf16;
typedef __bf16 bf16x4 __attribute__((ext_vector_type(4)));
typedef __bf16 bf16x8 __attribute__((ext_vector_type(8)));
typedef float  f32x4  __attribute__((ext_vector_type(4)));

// ---------------------------------------------------------------------------
// Kernel 1: RMSNorm + router logits + softmax/top-4 + routing lists.
// ---------------------------------------------------------------------------
__global__ __launch_bounds__(256) void k_rms_router(
    const float* __restrict__ x, const float* __restrict__ nw,
    const float* __restrict__ rw, const float* __restrict__ rb,
    const float* __restrict__ mw, const int* __restrict__ lidx,
    bf16* __restrict__ tB, float* __restrict__ out,
    int* __restrict__ cnt, int* __restrict__ tok_list,
    float* __restrict__ wgt_list)
{
    const int t = blockIdx.x, tid = threadIdx.x;
    const int lane = tid & 63, wave = tid >> 6;
    __shared__ float tbuf[H_];
    __shared__ float red[4];
    __shared__ float logits[E_];

    float4 xv = ((const float4*)(x + (size_t)t * H_))[tid];
    float4 wv = ((const float4*)nw)[tid];
    float ssq = xv.x*xv.x + xv.y*xv.y + xv.z*xv.z + xv.w*xv.w;
    #pragma unroll
    for (int off = 32; off; off >>= 1) ssq += __shfl_xor(ssq, off);
    if (lane == 0) red[wave] = ssq;
    __syncthreads();
    const float rms = rsqrtf((red[0] + red[1] + red[2] + red[3]) * (1.0f / H_) + 1e-5f);

    float4 tv;
    tv.x = xv.x * rms * wv.x;
    tv.y = xv.y * rms * wv.y;
    tv.z = xv.z * rms * wv.z;
    tv.w = xv.w * rms * wv.w;

    ((float4*)(out + (size_t)t * H_))[tid] = xv;      // residual init
    ((float4*)tbuf)[tid] = tv;
    bf16x4 tb = { (bf16)tv.x, (bf16)tv.y, (bf16)tv.z, (bf16)tv.w };
    *(bf16x4*)(tB + (size_t)t * H_ + tid * 4) = tb;
    __syncthreads();

    #pragma unroll
    for (int ei = 0; ei < 4; ++ei) {
        const int e = wave * 4 + ei;
        const float* wr = rw + (size_t)e * H_;
        float s = 0.f;
        #pragma unroll
        for (int j = 0; j < 16; ++j) {
            const int c = lane + j * 64;
            s += tbuf[c] * wr[c];
        }
        #pragma unroll
        for (int off = 32; off; off >>= 1) s += __shfl_xor(s, off);
        if (lane == 0) logits[e] = s + rb[e];
    }
    __syncthreads();

    if (tid == 0) {
        float g[E_];
        #pragma unroll
        for (int e = 0; e < E_; ++e) g[e] = logits[e];

        const int li = lidx[0];
        float ma = 0.f, lw[E_];
        #pragma unroll
        for (int e = 0; e < E_; ++e) { lw[e] = mw[li * E_ + e]; ma = fmaxf(ma, fabsf(lw[e])); }
        if (ma > 0.f) {
            float mx = -1e30f;
            for (int e = 0; e < E_; ++e) mx = fmaxf(mx, g[e]);
            float se = 0.f;
            for (int e = 0; e < E_; ++e) se += expf(g[e] - mx);
            const float lse = logf(se) + mx;
            float gl[E_], gmx = -1e30f, gmn = 1e30f;
            for (int e = 0; e < E_; ++e) { gl[e] = g[e] - lse; gmx = fmaxf(gmx, gl[e]); gmn = fminf(gmn, gl[e]); }
            for (int e = 0; e < E_; ++e) {
                if (lw[e] > 0.f)      gl[e] = gmx + 0.01f;
                else if (lw[e] < 0.f) gl[e] = gmn - 0.01f;
                g[e] = gl[e];
            }
        }

        float mx = -1e30f;
        #pragma unroll
        for (int e = 0; e < E_; ++e) mx = fmaxf(mx, g[e]);
        float p[E_];
        #pragma unroll
        for (int e = 0; e < E_; ++e) p[e] = expf(g[e] - mx);

        bool used[E_] = {};
        int   idx[TOPK];
        float twv[TOPK];
        float ssum = 0.f;
        for (int k = 0; k < TOPK; ++k) {
            int best = -1; float bv = -1e30f;
            for (int e = 0; e < E_; ++e)
                if (!used[e] && p[e] > bv) { bv = p[e]; best = e; }
            used[best] = true; idx[k] = best; twv[k] = bv; ssum += bv;
        }
        const float inv = 1.f / ssum;
        for (int k = 0; k < TOPK; ++k) {
            const int e = idx[k];
            const int slot = atomicAdd(&cnt[e], 1);
            tok_list[e * T_ + slot] = t;
            wgt_list[e * T_ + slot] = twv[k] * inv;
        }
    }
}

// ---------------------------------------------------------------------------
// Kernel 2: scan + tile table. tile i = (expert, m0) for each live 64-row tile.
// ---------------------------------------------------------------------------
__global__ void k_scan(const int* __restrict__ cnt, int* __restrict__ base,
                       int* __restrict__ tiln, int* __restrict__ tile_e,
                       int* __restrict__ tile_m0)
{
    if (threadIdx.x == 0) {
        int s = 0, nt = 0;
        for (int e = 0; e < E_; ++e) {
            base[e] = s; s += cnt[e];
            for (int m0 = 0; m0 < cnt[e]; m0 += 64) {
                if (nt < 96) { tile_e[nt] = e; tile_m0[nt] = m0; ++nt; }
            }
        }
        base[E_] = s;
        tiln[0] = nt;
    }
}

// ---------------------------------------------------------------------------
// Repack: W [E][1024(k)][Ndim(n)] fp32 -> bf16 MFMA-fragment tiles.
// out[((e*(Ndim/16) + nb)*32 + kb)*512 + l*8 + j] = W[e][kb*32+(l>>4)*8+j][nb*16+(l&15)]
// ---------------------------------------------------------------------------
__global__ __launch_bounds__(256) void k_repack(
    const float* __restrict__ W, bf16* __restrict__ out, int Ndim)
{
    __shared__ float tile[32][260];
    const int e = blockIdx.z, kb = blockIdx.y, n0 = blockIdx.x * 256;
    const int t = threadIdx.x;
    const int nbs = Ndim >> 4;

    const float* src = W + ((size_t)e * 1024 + (size_t)kb * 32) * Ndim + n0;
    #pragma unroll
    for (int i = 0; i < 8; ++i) {
        const int idx = i * 256 + t;
        const int k = idx >> 6, c4 = (idx & 63) * 4;
        float4 v = *(const float4*)(src + (size_t)k * Ndim + c4);
        *(float4*)&tile[k][c4] = v;
    }
    __syncthreads();

    const int f = t >> 4;
    const int lg = (t & 15) * 4;
    bf16* dst = out + (((size_t)(e * nbs + n0 / 16 + f)) * 32 + kb) * 512;
    #pragma unroll
    for (int li = 0; li < 4; ++li) {
        const int l = lg + li, q = l >> 4, r = l & 15;
        bf16x8 p;
        #pragma unroll
        for (int j = 0; j < 8; ++j) p[j] = (bf16)tile[q * 8 + j][f * 16 + r];
        *(bf16x8*)(dst + l * 8) = p;
    }
}

// ---------------------------------------------------------------------------
// Kernel 3: grouped gate_up GEMM. Tile-table grid, A staged in LDS in
// fragment order (shared by all 4 waves), B register-direct from packed
// weights with 1-iter register double-buffer. BM=64, BK=64, 16 iters.
// grid: (16, 80); wave w handles gate nb = bx*4+w and up nb = gate+64.
// ---------------------------------------------------------------------------
__global__ __launch_bounds__(256) void k_gateup3(
    const bf16* __restrict__ tB, const bf16* __restrict__ w13p,
    const float* __restrict__ b13, const int* __restrict__ cnt,
    const int* __restrict__ base, const int* __restrict__ tiln,
    const int* __restrict__ tile_e, const int* __restrict__ tile_m0,
    const int* __restrict__ tok_list, bf16* __restrict__ act)
{
    const int ti = blockIdx.y;
    if (ti >= tiln[0]) return;
    const int e  = tile_e[ti];
    const int m0 = tile_m0[ti];
    const int ne = cnt[e];

    const int tid = threadIdx.x, lane = tid & 63, wave = tid >> 6;
    const int q = lane >> 4, r = lane & 15;

    // A tile in LDS, fragment order: frag (mf,kc) at [(mf*2+kc)*64 + lane]*8
    __shared__ __align__(16) bf16 As[8 * 64 * 8];

    // --- staging coords: thread t -> row m = t>>2, 32B chunk kq = t&3 ---
    const int m   = tid >> 2, kq = tid & 3;
    const int mf_s = m >> 4, r_s = m & 15;
    const int kc_s = kq >> 1, q_s = (kq & 1) * 2;
    bf16* wr0 = As + ((size_t)((mf_s * 2 + kc_s) * 64 + q_s * 16 + r_s)) * 8;
    bf16* wr1 = wr0 + 16 * 8;
    int srow = m0 + m; srow = srow < ne ? srow : ne - 1;
    const bf16* pA = tB + (size_t)tok_list[e * T_ + srow] * H_ + kq * 16;

    const int nb_g = blockIdx.x * 4 + wave;
    const bf16* pBg = w13p + ((size_t)(e * 128 + nb_g     ) * 32) * 512 + lane * 8;
    const bf16* pBu = w13p + ((size_t)(e * 128 + nb_g + 64) * 32) * 512 + lane * 8;

    f32x4 accg[4] = {};
    f32x4 accu[4] = {};
    uint4 ar0a, ar0b, ar1a, ar1b;
    bf16x8 bg0[2], bu0[2], bg1[2], bu1[2];

#define LOADA(A0, A1) do { \
    A0 = *(const uint4*)pA; A1 = *(const uint4*)(pA + 8); pA += 64; } while (0)
#define STAGEA(A0, A1) do { \
    *(uint4*)wr0 = A0; *(uint4*)wr1 = A1; } while (0)
#define LOADB(BG, BU) do { \
    BG[0] = *(const bf16x8*)pBg; BG[1] = *(const bf16x8*)(pBg + 512); pBg += 1024; \
    BU[0] = *(const bf16x8*)pBu; BU[1] = *(const bf16x8*)(pBu + 512); pBu += 1024; } while (0)
#define COMPUTE(BG, BU) do { \
    _Pragma("unroll") \
    for (int kc = 0; kc < 2; ++kc) { \
        bf16x8 afr[4]; \
        _Pragma("unroll") \
        for (int mf = 0; mf < 4; ++mf) \
            afr[mf] = *(const bf16x8*)(As + ((size_t)((mf * 2 + kc) * 64 + lane)) * 8); \
        _Pragma("unroll") \
        for (int mf = 0; mf < 4; ++mf) { \
            accg[mf] = __builtin_amdgcn_mfma_f32_16x16x32_bf16(afr[mf], BG[kc], accg[mf], 0, 0, 0); \
            accu[mf] = __builtin_amdgcn_mfma_f32_16x16x32_bf16(afr[mf], BU[kc], accu[mf], 0, 0, 0); \
        } \
    } } while (0)

    LOADA(ar0a, ar0b);
    LOADB(bg0, bu0);
    #pragma unroll 2
    for (int kb = 0; kb < 16; kb += 2) {
        __syncthreads();
        STAGEA(ar0a, ar0b);
        LOADA(ar1a, ar1b);           // prefetch next A (last one reads junk, unused)
        LOADB(bg1, bu1);             // prefetch next B
        __syncthreads();
        COMPUTE(bg0, bu0);

        __syncthreads();
        STAGEA(ar1a, ar1b);
        LOADA(ar0a, ar0b);
        LOADB(bg0, bu0);
        __syncthreads();
        COMPUTE(bg1, bu1);
    }
#undef LOADA
#undef STAGEA
#undef LOADB
#undef COMPUTE

    // --- epilogue ---
    const int sb = base[e];
    const int cg = nb_g * 16 + r;                 // column in [0, IDIM)
    const float bgv = b13[e * 2 * IDIM + cg];
    const float buv = b13[e * 2 * IDIM + IDIM + cg];
    #pragma unroll
    for (int mf = 0; mf < 4; ++mf) {
        #pragma unroll
        for (int rg = 0; rg < 4; ++rg) {
            const int row = mf * 16 + q * 4 + rg;
            if (m0 + row < ne) {
                const float hg = accg[mf][rg] + bgv;
                const float hu = accu[mf][rg] + buv;
                const float gt = fminf(hg, LIMIT);
                const float up = fminf(fmaxf(hu, -LIMIT), LIMIT);
                const float av = (up + 1.0f) * gt / (1.0f + expf(-ALPHA * gt));
                act[(size_t)(sb + m0 + row) * IDIM + cg] = (bf16)av;
            }
        }
    }
}

// ---------------------------------------------------------------------------
// Kernel 4: grouped down GEMM + weighted atomic combine. Same structure.
// grid: (8, 80); wave w handles nb = bx*8 + w*2 + {0,1}.
// ---------------------------------------------------------------------------
__global__ __launch_bounds__(256) void k_down3(
    const bf16* __restrict__ act, const bf16* __restrict__ w2p,
    const float* __restrict__ b2, const int* __restrict__ cnt,
    const int* __restrict__ base, const int* __restrict__ tiln,
    const int* __restrict__ tile_e, const int* __restrict__ tile_m0,
    const int* __restrict__ tok_list, const float* __restrict__ wgt_list,
    float* __restrict__ out)
{
    const int ti = blockIdx.y;
    if (ti >= tiln[0]) return;
    const int e  = tile_e[ti];
    const int m0 = tile_m0[ti];
    const int ne = cnt[e];
    const int sb = base[e];

    const int tid = threadIdx.x, lane = tid & 63, wave = tid >> 6;
    const int q = lane >> 4, r = lane & 15;

    __shared__ __align__(16) bf16 As[8 * 64 * 8];

    const int m   = tid >> 2, kq = tid & 3;
    const int mf_s = m >> 4, r_s = m & 15;
    const int kc_s = kq >> 1, q_s = (kq & 1) * 2;
    bf16* wr0 = As + ((size_t)((mf_s * 2 + kc_s) * 64 + q_s * 16 + r_s)) * 8;
    bf16* wr1 = wr0 + 16 * 8;
    int srow = m0 + m; srow = srow < ne ? srow : ne - 1;
    const bf16* pA = act + (size_t)(sb + srow) * IDIM + kq * 16;

    const int nb0 = blockIdx.x * 8 + wave * 2;
    const bf16* pB0 = w2p + ((size_t)(e * 64 + nb0    ) * 32) * 512 + lane * 8;
    const bf16* pB1 = w2p + ((size_t)(e * 64 + nb0 + 1) * 32) * 512 + lane * 8;

    f32x4 acc[4][2] = {};
    uint4 ar0a, ar0b, ar1a, ar1b;
    bf16x8 bA0[2], bB0[2], bA1[2], bB1[2];   // [nf][kc] buffers x2 stages

#define LOADA(A0, A1) do { \
    A0 = *(const uint4*)pA; A1 = *(const uint4*)(pA + 8); pA += 64; } while (0)
#define STAGEA(A0, A1) do { \
    *(uint4*)wr0 = A0; *(uint4*)wr1 = A1; } while (0)
#define LOADB(B0, B1) do { \
    B0[0] = *(const bf16x8*)pB0; B0[1] = *(const bf16x8*)(pB0 + 512); pB0 += 1024; \
    B1[0] = *(const bf16x8*)pB1; B1[1] = *(const bf16x8*)(pB1 + 512); pB1 += 1024; } while (0)
#define COMPUTE(B0, B1) do { \
    _Pragma("unroll") \
    for (int kc = 0; kc < 2; ++kc) { \
        bf16x8 afr[4]; \
        _Pragma("unroll") \
        for (int mf = 0; mf < 4; ++mf) \
            afr[mf] = *(const bf16x8*)(As + ((size_t)((mf * 2 + kc) * 64 + lane)) * 8); \
        _Pragma("unroll") \
        for (int mf = 0; mf < 4; ++mf) { \
            acc[mf][0] = __builtin_amdgcn_mfma_f32_16x16x32_bf16(afr[mf], B0[kc], acc[mf][0], 0, 0, 0); \
            acc[mf][1] = __builtin_amdgcn_mfma_f32_16x16x32_bf16(afr[mf], B1[kc], acc[mf][1], 0, 0, 0); \
        } \
    } } while (0)

    LOADA(ar0a, ar0b);
    LOADB(bA0, bB0);
    #pragma unroll 2
    for (int kb = 0; kb < 16; kb += 2) {
        __syncthreads();
        STAGEA(ar0a, ar0b);
        LOADA(ar1a, ar1b);
        LOADB(bA1, bB1);
        __syncthreads();
        COMPUTE(bA0, bB0);

        __syncthreads();
        STAGEA(ar1a, ar1b);
        LOADA(ar0a, ar0b);
        LOADB(bA0, bB0);
        __syncthreads();
        COMPUTE(bA1, bB1);
    }
#undef LOADA
#undef STAGEA
#undef LOADB
#undef COMPUTE

    #pragma unroll
    for (int nf = 0; nf < 2; ++nf) {
        const int ch = (nb0 + nf) * 16 + r;
        const float bb = b2[e * H_ + ch];
        #pragma unroll
        for (int mf = 0; mf < 4; ++mf) {
            #pragma unroll
            for (int rg = 0; rg < 4; ++rg) {
                const int row = mf * 16 + q * 4 + rg;
                const int s = m0 + row;
                if (s < ne) {
                    const int   tok = tok_list[e * T_ + s];
                    const float w   = wgt_list[e * T_ + s];
                    atomicAdd(&out[(size_t)tok * H_ + ch], w * (acc[mf][nf][rg] + bb));
                }
            }
        }
    }
}

// ---------------------------------------------------------------------------
// Fallback (round-1) GEMMs, used if ws too small for packed weights.
// ---------------------------------------------------------------------------
__global__ __launch_bounds__(256) void k_gateup(
    const bf16* __restrict__ tB, const float* __restrict__ w13,
    const float* __restrict__ b13, const int* __restrict__ cnt,
    const int* __restrict__ base, const int* __restrict__ tok_list,
    bf16* __restrict__ act)
{
    const int e  = blockIdx.z;
    const int ne = cnt[e];
    const int m0 = blockIdx.y * 64;
    if (m0 >= ne) return;
    const int n0  = blockIdx.x * 64;
    const int tid = threadIdx.x, lane = tid & 63, wave = tid >> 6;

    __shared__ __align__(16) bf16 As[64][40];
    __shared__ __align__(16) bf16 Bg[64][40];
    __shared__ __align__(16) bf16 Bu[64][40];
    __shared__ int stok[64];

    if (tid < 64) {
        const int s = m0 + tid;
        stok[tid] = (s < ne) ? tok_list[e * T_ + s] : -1;
    }
    __syncthreads();

    const int ar = tid >> 2, ak = (tid & 3) * 8;
    const int atok = stok[ar];
    const int bn = tid & 63, bk = wave * 8;
    const size_t wrow = (size_t)(2 * IDIM);
    const float* wbase = w13 + (size_t)e * H_ * wrow + n0 + bn;

    const int wm = wave >> 1, wn = wave & 1;
    const int q = lane >> 4, r = lane & 15;
    f32x4 accg[2][2] = {};
    f32x4 accu[2][2] = {};

    for (int kb = 0; kb < H_ / 32; ++kb) {
        __syncthreads();
        uint4 av = make_uint4(0u, 0u, 0u, 0u);
        if (atok >= 0)
            av = *(const uint4*)(tB + (size_t)atok * H_ + kb * 32 + ak);
        *(uint4*)&As[ar][ak] = av;
        {
            const float* src = wbase + (size_t)(kb * 32 + bk) * wrow;
            bf16x8 pg, pu;
            #pragma unroll
            for (int j = 0; j < 8; ++j) {
                pg[j] = (bf16)src[(size_t)j * wrow];
                pu[j] = (bf16)src[(size_t)j * wrow + IDIM];
            }
            *(bf16x8*)&Bg[bn][bk] = pg;
            *(bf16x8*)&Bu[bn][bk] = pu;
        }
        __syncthreads();
        bf16x8 a[2], bg[2], bu[2];
        a[0]  = *(const bf16x8*)&As[wm * 32 +      r][q * 8];
        a[1]  = *(const bf16x8*)&As[wm * 32 + 16 + r][q * 8];
        bg[0] = *(const bf16x8*)&Bg[wn * 32 +      r][q * 8];
        bg[1] = *(const bf16x8*)&Bg[wn * 32 + 16 + r][q * 8];
        bu[0] = *(const bf16x8*)&Bu[wn * 32 +      r][q * 8];
        bu[1] = *(const bf16x8*)&Bu[wn * 32 + 16 + r][q * 8];
        #pragma unroll
        for (int im = 0; im < 2; ++im)
            #pragma unroll
            for (int in = 0; in < 2; ++in) {
                accg[im][in] = __builtin_amdgcn_mfma_f32_16x16x32_bf16(a[im], bg[in], accg[im][in], 0, 0, 0);
                accu[im][in] = __builtin_amdgcn_mfma_f32_16x16x32_bf16(a[im], bu[in], accu[im][in], 0, 0, 0);
            }
    }

    const int sb = base[e];
    #pragma unroll
    for (int im = 0; im < 2; ++im)
        #pragma unroll
        for (int in = 0; in < 2; ++in)
            #pragma unroll
            for (int rg = 0; rg < 4; ++rg) {
                const int row = wm * 32 + im * 16 + q * 4 + rg;
                const int col = wn * 32 + in * 16 + r;
                if (m0 + row < ne) {
                    const float hg = accg[im][in][rg] + b13[e * 2 * IDIM + n0 + col];
                    const float hu = accu[im][in][rg] + b13[e * 2 * IDIM + IDIM + n0 + col];
                    const float gt = fminf(hg, LIMIT);
                    const float up = fminf(fmaxf(hu, -LIMIT), LIMIT);
                    const float av = (up + 1.0f) * gt / (1.0f + expf(-ALPHA * gt));
                    act[(size_t)(sb + m0 + row) * IDIM + n0 + col] = (bf16)av;
                }
            }
}

__global__ __launch_bounds__(256) void k_down(
    const bf16* __restrict__ act, const float* __restrict__ w2,
    const float* __restrict__ b2, const int* __restrict__ cnt,
    const int* __restrict__ base, const int* __restrict__ tok_list,
    const float* __restrict__ wgt_list, float* __restrict__ out)
{
    const int e  = blockIdx.z;
    const int ne = cnt[e];
    const int m0 = blockIdx.y * 64;
    if (m0 >= ne) return;
    const int n0  = blockIdx.x * 64;
    const int tid = threadIdx.x, lane = tid & 63, wave = tid >> 6;

    __shared__ __align__(16) bf16 As[64][40];
    __shared__ __align__(16) bf16 Bs[64][40];
    __shared__ int   stok[64];
    __shared__ float swgt[64];

    if (tid < 64) {
        const int s = m0 + tid;
        stok[tid] = (s < ne) ? tok_list[e * T_ + s] : -1;
        swgt[tid] = (s < ne) ? wgt_list[e * T_ + s] : 0.f;
    }
    __syncthreads();

    const int sb = base[e];
    const int ar = tid >> 2, ak = (tid & 3) * 8;
    const bool arow_ok = (m0 + ar) < ne;
    const int bn = tid & 63, bk = wave * 8;
    const float* wbase = w2 + (size_t)e * IDIM * H_ + n0 + bn;

    const int wm = wave >> 1, wn = wave & 1;
    const int q = lane >> 4, r = lane & 15;
    f32x4 acc[2][2] = {};

    for (int kb = 0; kb < IDIM / 32; ++kb) {
        __syncthreads();
        uint4 av = make_uint4(0u, 0u, 0u, 0u);
        if (arow_ok)
            av = *(const uint4*)(act + (size_t)(sb + m0 + ar) * IDIM + kb * 32 + ak);
        *(uint4*)&As[ar][ak] = av;
        {
            const float* src = wbase + (size_t)(kb * 32 + bk) * H_;
            bf16x8 pb;
            #pragma unroll
            for (int j = 0; j < 8; ++j) pb[j] = (bf16)src[(size_t)j * H_];
            *(bf16x8*)&Bs[bn][bk] = pb;
        }
        __syncthreads();
        bf16x8 a[2], b[2];
        a[0] = *(const bf16x8*)&As[wm * 32 +      r][q * 8];
        a[1] = *(const bf16x8*)&As[wm * 32 + 16 + r][q * 8];
        b[0] = *(const bf16x8*)&Bs[wn * 32 +      r][q * 8];
        b[1] = *(const bf16x8*)&Bs[wn * 32 + 16 + r][q * 8];
        #pragma unroll
        for (int im = 0; im < 2; ++im)
            #pragma unroll
            for (int in = 0; in < 2; ++in)
                acc[im][in] = __builtin_amdgcn_mfma_f32_16x16x32_bf16(a[im], b[in], acc[im][in], 0, 0, 0);
    }

    #pragma unroll
    for (int im = 0; im < 2; ++im)
        #pragma unroll
        for (int in = 0; in < 2; ++in)
            #pragma unroll
            for (int rg = 0; rg < 4; ++rg) {
                const int row = wm * 32 + im * 16 + q * 4 + rg;
                const int col = wn * 32 + in * 16 + r;
                if (m0 + row < ne) {
                    const int   tok = stok[row];
                    const float w   = swgt[row];
                    atomicAdd(&out[(size_t)tok * H_ + n0 + col], w * (acc[im][in][rg] + b2[e * H_ + n0 + col]));
                }
            }
}

// ---------------------------------------------------------------------------
extern "C" void kernel_launch(void* const* d_in, const int* in_sizes, int n_in,
                              void* d_out, int out_size, void* d_ws, size_t ws_size,
                              hipStream_t stream)
{
    const float* x        = (const float*)d_in[0];
    const float* norm_w   = (const float*)d_in[1];
    const float* router_w = (const float*)d_in[2];
    const float* router_b = (const float*)d_in[3];
    const float* w13      = (const float*)d_in[4];
    const float* b13      = (const float*)d_in[5];
    const float* w2       = (const float*)d_in[6];
    const float* b2       = (const float*)d_in[7];
    const float* manual_w = (const float*)d_in[8];
    const int*   layer_i  = (const int*)d_in[9];
    float* out = (float*)d_out;

    char* ws = (char*)d_ws;
    bf16*  tB   = (bf16*)ws;                              // 2 MB @ 0
    bf16*  act  = (bf16*)(ws + (2ull << 20));             // 8 MB @ 2M
    char*  meta = ws + (10ull << 20);
    int*   cnt      = (int*)meta;                         // 16 ints
    int*   basep    = (int*)(meta + 64);                  // 17 ints
    int*   tiln     = (int*)(meta + 256);                 // 1 int
    int*   tile_e   = (int*)(meta + 512);                 // 96 ints
    int*   tile_m0  = (int*)(meta + 1024);                // 96 ints
    int*   tok_list = (int*)(meta + (16ull << 10));       // 64 KB
    float* wgt_list = (float*)(meta + (16ull << 10) + (64ull << 10)); // 64 KB
    bf16*  w13p     = (bf16*)(ws + (12ull << 20));        // 64 MB
    bf16*  w2p      = (bf16*)(ws + (76ull << 20));        // 32 MB

    const bool fast = ws_size >= (108ull << 20);

    hipMemsetAsync(cnt, 0, E_ * sizeof(int), stream);

    k_rms_router<<<T_, 256, 0, stream>>>(x, norm_w, router_w, router_b,
                                         manual_w, layer_i, tB, out,
                                         cnt, tok_list, wgt_list);
    k_scan<<<1, 64, 0, stream>>>(cnt, basep, tiln, tile_e, tile_m0);

    if (fast) {
        dim3 gr13(2 * IDIM / 256, 32, E_);
        k_repack<<<gr13, 256, 0, stream>>>(w13, w13p, 2 * IDIM);
        dim3 gr2(H_ / 256, 32, E_);
        k_repack<<<gr2, 256, 0, stream>>>(w2, w2p, H_);

        dim3 gg(16, 80);
        k_gateup3<<<gg, 256, 0, stream>>>(tB, w13p, b13, cnt, basep, tiln,
                                          tile_e, tile_m0, tok_list, act);
        dim3 gd(8, 80);
        k_down3<<<gd, 256, 0, stream>>>(act, w2p, b2, cnt, basep, tiln,
                                        tile_e, tile_m0, tok_list, wgt_list, out);
    } else {
        dim3 gg(IDIM / 64, T_ / 64, E_);
        k_gateup<<<gg, 256, 0, stream>>>(tB, w13, b13, cnt, basep, tok_list, act);
        dim3 gd(H_ / 64, T_ / 64, E_);
        k_down<<<gd, 256, 0, stream>>>(act, w2, b2, cnt, basep, tok_list, wgt_list, out);
    }
}